// Round 17
// baseline (89.211 us; speedup 1.0000x reference)
//
#include <hip/hip_runtime.h>
#include <hip/hip_bf16.h>
#include <math.h>

// Problem constants (from reference setup_inputs)
constexpr int B_  = 8;
constexpr int CIN = 3;
constexpr int C_  = 64;
constexpr int H_  = 256;
constexpr int W_  = 256;
constexpr int TAPS = 9;   // K*K, K=3
constexpr int KROW = TAPS * W_ / 2;   // u32 words per bf16 kern row (1152)

typedef float f32x4 __attribute__((ext_vector_type(4)));
typedef unsigned int u32x2 __attribute__((ext_vector_type(2)));
typedef unsigned int u32x4 __attribute__((ext_vector_type(4)));

static __device__ __forceinline__ unsigned short f2bf(float f) {
    // RNE f32 -> bf16 (no NaN handling needed for this data)
    unsigned int u = __float_as_uint(f);
    unsigned int r = (u + 0x7fffu + ((u >> 16) & 1u)) >> 16;
    return (unsigned short)r;
}

// ============================================================================
// Kernel 1 (compute-bound, at fp32 VALU roofline): kern in BF16
// ============================================================================
__global__ __launch_bounds__(256, 4)
void hsa_kern(const float* __restrict__ lr,
              const float* __restrict__ w1,
              const float* __restrict__ b1,
              const float* __restrict__ w2,
              const float* __restrict__ b2,
              unsigned short* __restrict__ kws)
{
    __shared__ float w2t[C_][12];       // transposed 1x1 weights

    const int tid = threadIdx.x;
    const int blk = blockIdx.x;         // 0 .. B_*H_-1
    const int b = blk / H_;
    const int y = blk % H_;

    for (int i = tid; i < TAPS * C_; i += 256) {
        const int t = i / C_;
        const int c = i % C_;
        w2t[c][t] = w2[i];
    }
    __syncthreads();

    const int x = tid;                  // 0..255
    float win[CIN][3][3];
    #pragma unroll
    for (int ci = 0; ci < CIN; ++ci) {
        #pragma unroll
        for (int r = 0; r < 3; ++r) {
            const int yy = y + r - 1;
            const bool vy = (unsigned)yy < (unsigned)H_;
            const float* row = lr + ((size_t)(b * CIN + ci) * H_ + yy) * W_;
            win[ci][r][0] = (vy && x > 0)       ? row[x - 1] : 0.f;
            win[ci][r][1] = vy                   ? row[x]     : 0.f;
            win[ci][r][2] = (vy && x < W_ - 1)  ? row[x + 1] : 0.f;
        }
    }

    float acc[TAPS];
    #pragma unroll
    for (int t = 0; t < TAPS; ++t) acc[t] = b2[t];

    for (int c = 0; c < C_; ++c) {
        const float* wc = w1 + c * 27;
        float h0 = b1[c], h1 = 0.f, h2 = 0.f;
        #pragma unroll
        for (int r = 0; r < 3; ++r)
            #pragma unroll
            for (int j = 0; j < 3; ++j) {
                h0 = fmaf(wc[(0 * 3 + r) * 3 + j], win[0][r][j], h0);
                h1 = fmaf(wc[(1 * 3 + r) * 3 + j], win[1][r][j], h1);
                h2 = fmaf(wc[(2 * 3 + r) * 3 + j], win[2][r][j], h2);
            }
        const float hsum = fmaxf((h0 + h1) + h2, 0.f);   // ReLU

        const float4 wa = *(const float4*)&w2t[c][0];
        const float4 wb = *(const float4*)&w2t[c][4];
        const float  w8 = w2t[c][8];
        acc[0] = fmaf(wa.x, hsum, acc[0]);
        acc[1] = fmaf(wa.y, hsum, acc[1]);
        acc[2] = fmaf(wa.z, hsum, acc[2]);
        acc[3] = fmaf(wa.w, hsum, acc[3]);
        acc[4] = fmaf(wb.x, hsum, acc[4]);
        acc[5] = fmaf(wb.y, hsum, acc[5]);
        acc[6] = fmaf(wb.z, hsum, acc[6]);
        acc[7] = fmaf(wb.w, hsum, acc[7]);
        acc[8] = fmaf(w8,  hsum, acc[8]);
    }

    unsigned short* kr = kws + (size_t)(b * H_ + y) * (TAPS * W_);
    #pragma unroll
    for (int t = 0; t < TAPS; ++t) kr[t * W_ + x] = f2bf(acc[t]);
}

// ============================================================================
// Kernel 2 (gate): out = h * sigmoid(sum_taps shifted(h) * kern)
// R16 structure with two final levers (R17):
//  (a) NO XCD swizzle — the swizzle (in every gate since R4, never A/B'd)
//      confines each batch to one XCD; suspect it caps per-XCD read+write
//      fabric throughput at ~390 GB/s (8x390 = the observed ~3.1 TB/s wall;
//      copy achieves ~790/XCD). Natural order spreads neighbors across XCDs.
//  (b) kern rows expanded to f32 in LDS ONCE per block (74 KB coop stage):
//      per-iter kt = 9x ds_read_b128, no bf16 expand, ~40 fewer VALU/iter
//      (VALUBusy was 28%, the highest residual counter).
// Steady state per wave per iter: 1 h load + 1 NT store (copy-shaped).
// ============================================================================
__global__ __launch_bounds__(256, 2)
void hsa_gate(const float* __restrict__ hin,
              const unsigned short* __restrict__ kws,
              float* __restrict__ out)
{
    __shared__ float ksh[8 * TAPS * W_];   // 73728 B: 8 kern rows, f32

    const int tid = threadIdx.x;
    const int bid = blockIdx.x;          // 0..4095 — NATURAL order this round
    const int b     = bid >> 9;          // 0..7
    const int strip = (bid >> 4) & 31;   // 0..31
    const int cg    = bid & 15;          // 0..15
    const int Y     = strip * 8;

    const int lane = tid & 63;
    const int wv   = tid >> 6;           // 0..3
    const int x0   = lane * 4;
    const int c0   = cg * 4 + wv;        // this wave's single channel

    const size_t plane = (size_t)H_ * W_;
    const float* hb = hin + ((size_t)b * C_ + c0) * plane;
    float*       ob = out + ((size_t)b * C_ + c0) * plane;
    const unsigned int* kbase = (const unsigned int*)kws + (size_t)b * H_ * KROW;

    const float lmask = (lane > 0)  ? 1.f : 0.f;
    const float rmask = (lane < 63) ? 1.f : 0.f;

    // ---- stage 8 kern rows cooperatively, expanding bf16 -> f32 once ----
    // rows Y..Y+7 are contiguous: 8*KROW = 9216 u32 -> 18432 f32 (73.7 KB)
    {
        const unsigned int* kr = kbase + (size_t)Y * KROW;
        #pragma unroll
        for (int i = 0; i < 36; ++i) {
            const int idx = tid + i * 256;       // 0..9215
            const unsigned int w = kr[idx];
            ksh[2 * idx]     = __uint_as_float(w << 16);
            ksh[2 * idx + 1] = __uint_as_float(w & 0xffff0000u);
        }
    }

    // ---- prologue: 3-row h window for this wave's channel ----
    f32x4 wA, wB, wC;
    {
        const int ym = (Y > 0) ? (Y - 1) : 0;   // clamped; masked via kt
        wA = *(const f32x4*)(hb + (size_t)ym      * W_ + x0);
        wB = *(const f32x4*)(hb + (size_t)Y       * W_ + x0);
        wC = *(const f32x4*)(hb + (size_t)(Y + 1) * W_ + x0);
    }
    __syncthreads();   // kern staging visible; only barrier in the kernel

    #pragma unroll
    for (int yy = 0; yy < 8; ++yy) {
        const int yg = Y + yy;

        // next h row (the wave's ONLY VMEM load this iter; sequential stream)
        f32x4 nxt;
        if (yy < 7) {
            const int yn = (yg + 2 < H_) ? (yg + 2) : (H_ - 1);
            nxt = *(const f32x4*)(hb + (size_t)yn * W_ + x0);
        }

        // kern taps straight from LDS (already f32)
        f32x4 kt[TAPS];
        #pragma unroll
        for (int t = 0; t < TAPS; ++t)
            kt[t] = *(const f32x4*)&ksh[(yy * TAPS + t) * W_ + x0];

        // fold ALL boundary masks into kt
        const float m0 = (yg > 0)      ? 1.f : 0.f;
        const float m2 = (yg < H_ - 1) ? 1.f : 0.f;
        #pragma unroll
        for (int t = 0; t < 3; ++t) { kt[t] *= m0; kt[6 + t] *= m2; }
        kt[0].x *= lmask; kt[3].x *= lmask; kt[6].x *= lmask;
        kt[2].w *= rmask; kt[5].w *= rmask; kt[8].w *= rmask;

        // compute this channel (pure FMA + 2 shuffles per window row)
        float sim0 = 0.f, sim1 = 0.f, sim2 = 0.f, sim3 = 0.f;
        #pragma unroll
        for (int r = 0; r < 3; ++r) {
            const f32x4 cv = (r == 0) ? wA : (r == 1) ? wB : wC;
            const float l  = __shfl_up(cv.w, 1);    // x0-1 (lane0 masked via kt)
            const float rr = __shfl_down(cv.x, 1);  // x0+4 (lane63 masked via kt)
            const f32x4 k0 = kt[r * 3 + 0];
            const f32x4 k1 = kt[r * 3 + 1];
            const f32x4 k2 = kt[r * 3 + 2];
            sim0 = fmaf(l,    k0.x, fmaf(cv.x, k1.x, fmaf(cv.y, k2.x, sim0)));
            sim1 = fmaf(cv.x, k0.y, fmaf(cv.y, k1.y, fmaf(cv.z, k2.y, sim1)));
            sim2 = fmaf(cv.y, k0.z, fmaf(cv.z, k1.z, fmaf(cv.w, k2.z, sim2)));
            sim3 = fmaf(cv.z, k0.w, fmaf(cv.w, k1.w, fmaf(rr,   k2.w, sim3)));
        }

        // gate + non-temporal store (sequential write stream)
        f32x4 o;
        o.x = wB.x * __builtin_amdgcn_rcpf(1.f + __expf(-sim0));
        o.y = wB.y * __builtin_amdgcn_rcpf(1.f + __expf(-sim1));
        o.z = wB.z * __builtin_amdgcn_rcpf(1.f + __expf(-sim2));
        o.w = wB.w * __builtin_amdgcn_rcpf(1.f + __expf(-sim3));
        __builtin_nontemporal_store(o, (f32x4*)(ob + (size_t)yg * W_ + x0));

        // slide window (SSA renames after full unroll)
        if (yy < 7) { wA = wB; wB = wC; wC = nxt; }
    }
}

// ============================================================================
// Fallback: single fused kernel (used only if ws_size is too small)
// ============================================================================
__global__ __launch_bounds__(256, 4)
void hsa_fused(const float* __restrict__ lr,
               const float* __restrict__ hin,
               const float* __restrict__ w1,
               const float* __restrict__ b1,
               const float* __restrict__ w2,
               const float* __restrict__ b2,
               float* __restrict__ out)
{
    __shared__ float kernS[TAPS][W_];
    __shared__ float w2t[C_][12];

    const int tid = threadIdx.x;
    const int blk = blockIdx.x;
    const int b = blk / H_;
    const int y = blk % H_;

    for (int i = tid; i < TAPS * C_; i += 256) {
        const int t = i / C_;
        const int c = i % C_;
        w2t[c][t] = w2[i];
    }
    __syncthreads();

    {
        const int x = tid;
        float win[CIN][3][3];
        #pragma unroll
        for (int ci = 0; ci < CIN; ++ci)
            #pragma unroll
            for (int r = 0; r < 3; ++r) {
                const int yy = y + r - 1;
                const bool vy = (unsigned)yy < (unsigned)H_;
                const float* row = lr + ((size_t)(b * CIN + ci) * H_ + yy) * W_;
                win[ci][r][0] = (vy && x > 0)      ? row[x - 1] : 0.f;
                win[ci][r][1] = vy                  ? row[x]     : 0.f;
                win[ci][r][2] = (vy && x < W_ - 1) ? row[x + 1] : 0.f;
            }

        float acc[TAPS];
        #pragma unroll
        for (int t = 0; t < TAPS; ++t) acc[t] = b2[t];

        for (int c = 0; c < C_; ++c) {
            const float* wc = w1 + c * 27;
            float h0 = b1[c], h1 = 0.f, h2 = 0.f;
            #pragma unroll
            for (int r = 0; r < 3; ++r)
                #pragma unroll
                for (int j = 0; j < 3; ++j) {
                    h0 = fmaf(wc[(0 * 3 + r) * 3 + j], win[0][r][j], h0);
                    h1 = fmaf(wc[(1 * 3 + r) * 3 + j], win[1][r][j], h1);
                    h2 = fmaf(wc[(2 * 3 + r) * 3 + j], win[2][r][j], h2);
                }
            const float hsum = fmaxf((h0 + h1) + h2, 0.f);
            const float4 wa = *(const float4*)&w2t[c][0];
            const float4 wb = *(const float4*)&w2t[c][4];
            const float  w8 = w2t[c][8];
            acc[0] = fmaf(wa.x, hsum, acc[0]);
            acc[1] = fmaf(wa.y, hsum, acc[1]);
            acc[2] = fmaf(wa.z, hsum, acc[2]);
            acc[3] = fmaf(wa.w, hsum, acc[3]);
            acc[4] = fmaf(wb.x, hsum, acc[4]);
            acc[5] = fmaf(wb.y, hsum, acc[5]);
            acc[6] = fmaf(wb.z, hsum, acc[6]);
            acc[7] = fmaf(wb.w, hsum, acc[7]);
            acc[8] = fmaf(w8,  hsum, acc[8]);
        }
        #pragma unroll
        for (int t = 0; t < TAPS; ++t) kernS[t][x] = acc[t];
    }
    __syncthreads();

    const int lane = tid & 63;
    const int wav  = tid >> 6;
    const int x0   = lane * 4;

    float4 kt[TAPS];
    #pragma unroll
    for (int t = 0; t < TAPS; ++t) kt[t] = *(const float4*)&kernS[t][x0];

    #pragma unroll 4
    for (int cc = 0; cc < 16; ++cc) {
        const int c = wav * 16 + cc;
        const float* hb = hin + (size_t)(b * C_ + c) * H_ * W_;

        float4 rowv[3];
        float  lft[3], rgt[3];
        #pragma unroll
        for (int r = 0; r < 3; ++r) {
            const int yy = y + r - 1;
            const bool vy = (unsigned)yy < (unsigned)H_;
            float4 m;
            if (vy) m = *(const float4*)(hb + (size_t)yy * W_ + x0);
            else    m = make_float4(0.f, 0.f, 0.f, 0.f);
            rowv[r] = m;
            float l  = __shfl_up(m.w, 1);
            float rr = __shfl_down(m.x, 1);
            if (lane == 0)  l  = 0.f;
            if (lane == 63) rr = 0.f;
            lft[r] = l; rgt[r] = rr;
        }

        float sim0 = 0.f, sim1 = 0.f, sim2 = 0.f, sim3 = 0.f;
        #pragma unroll
        for (int r = 0; r < 3; ++r) {
            const float w6_0 = lft[r];
            const float w6_1 = rowv[r].x;
            const float w6_2 = rowv[r].y;
            const float w6_3 = rowv[r].z;
            const float w6_4 = rowv[r].w;
            const float w6_5 = rgt[r];
            { const float4 k4 = kt[r*3+0];
              sim0 = fmaf(w6_0, k4.x, sim0); sim1 = fmaf(w6_1, k4.y, sim1);
              sim2 = fmaf(w6_2, k4.z, sim2); sim3 = fmaf(w6_3, k4.w, sim3); }
            { const float4 k4 = kt[r*3+1];
              sim0 = fmaf(w6_1, k4.x, sim0); sim1 = fmaf(w6_2, k4.y, sim1);
              sim2 = fmaf(w6_3, k4.z, sim2); sim3 = fmaf(w6_4, k4.w, sim3); }
            { const float4 k4 = kt[r*3+2];
              sim0 = fmaf(w6_2, k4.x, sim0); sim1 = fmaf(w6_3, k4.y, sim1);
              sim2 = fmaf(w6_4, k4.z, sim2); sim3 = fmaf(w6_5, k4.w, sim3); }
        }

        float4 o;
        o.x = rowv[1].x * __builtin_amdgcn_rcpf(1.f + __expf(-sim0));
        o.y = rowv[1].y * __builtin_amdgcn_rcpf(1.f + __expf(-sim1));
        o.z = rowv[1].z * __builtin_amdgcn_rcpf(1.f + __expf(-sim2));
        o.w = rowv[1].w * __builtin_amdgcn_rcpf(1.f + __expf(-sim3));
        *(float4*)(out + ((size_t)(b * C_ + c) * H_ + y) * W_ + x0) = o;
    }
}

extern "C" void kernel_launch(void* const* d_in, const int* in_sizes, int n_in,
                              void* d_out, int out_size, void* d_ws, size_t ws_size,
                              hipStream_t stream) {
    const float* lr  = (const float*)d_in[0];  // [8,3,256,256]
    const float* hin = (const float*)d_in[1];  // [8,64,256,256]
    const float* w1  = (const float*)d_in[2];  // [64,3,3,3]
    const float* b1  = (const float*)d_in[3];  // [64]
    const float* w2  = (const float*)d_in[4];  // [9,64,1,1]
    const float* b2  = (const float*)d_in[5];  // [9]
    float* out = (float*)d_out;                // [8,64,256,256]

    const size_t kern_bytes = (size_t)B_ * H_ * TAPS * W_ * sizeof(unsigned short);

    if (ws_size >= kern_bytes) {
        unsigned short* kws = (unsigned short*)d_ws;
        hipLaunchKernelGGL(hsa_kern, dim3(B_ * H_), dim3(256), 0, stream,
                           lr, w1, b1, w2, b2, kws);
        // 8 batches x 32 strips(8 rows) x 16 channel-groups(4ch) = 4096 blocks
        hipLaunchKernelGGL(hsa_gate, dim3(4096), dim3(256), 0, stream,
                           hin, kws, out);
    } else {
        hipLaunchKernelGGL(hsa_fused, dim3(B_ * H_), dim3(256), 0, stream,
                           lr, hin, w1, b1, w2, b2, out);
    }
}

// Round 18
// 82.772 us; speedup vs baseline: 1.0778x; 1.0778x over previous
//
#include <hip/hip_runtime.h>
#include <hip/hip_bf16.h>
#include <math.h>

// Problem constants (from reference setup_inputs)
constexpr int B_  = 8;
constexpr int CIN = 3;
constexpr int C_  = 64;
constexpr int H_  = 256;
constexpr int W_  = 256;
constexpr int TAPS = 9;   // K*K, K=3
constexpr int KROW = TAPS * W_ / 2;   // u32 words per bf16 kern row (1152)

typedef float f32x4 __attribute__((ext_vector_type(4)));
typedef unsigned int u32x2 __attribute__((ext_vector_type(2)));
typedef unsigned int u32x4 __attribute__((ext_vector_type(4)));

static __device__ __forceinline__ unsigned short f2bf(float f) {
    // RNE f32 -> bf16 (no NaN handling needed for this data)
    unsigned int u = __float_as_uint(f);
    unsigned int r = (u + 0x7fffu + ((u >> 16) & 1u)) >> 16;
    return (unsigned short)r;
}

// ============================================================================
// Kernel 1 (compute-bound): kern = conv1x1(relu(conv3x3(lr))), BF16 out
// ============================================================================
__global__ __launch_bounds__(256, 4)
void hsa_kern(const float* __restrict__ lr,
              const float* __restrict__ w1,
              const float* __restrict__ b1,
              const float* __restrict__ w2,
              const float* __restrict__ b2,
              unsigned short* __restrict__ kws)
{
    __shared__ float w2t[C_][12];       // transposed 1x1 weights

    const int tid = threadIdx.x;
    const int blk = blockIdx.x;         // 0 .. B_*H_-1
    const int b = blk / H_;
    const int y = blk % H_;

    for (int i = tid; i < TAPS * C_; i += 256) {
        const int t = i / C_;
        const int c = i % C_;
        w2t[c][t] = w2[i];
    }
    __syncthreads();

    const int x = tid;                  // 0..255
    float win[CIN][3][3];
    #pragma unroll
    for (int ci = 0; ci < CIN; ++ci) {
        #pragma unroll
        for (int r = 0; r < 3; ++r) {
            const int yy = y + r - 1;
            const bool vy = (unsigned)yy < (unsigned)H_;
            const float* row = lr + ((size_t)(b * CIN + ci) * H_ + yy) * W_;
            win[ci][r][0] = (vy && x > 0)       ? row[x - 1] : 0.f;
            win[ci][r][1] = vy                   ? row[x]     : 0.f;
            win[ci][r][2] = (vy && x < W_ - 1)  ? row[x + 1] : 0.f;
        }
    }

    float acc[TAPS];
    #pragma unroll
    for (int t = 0; t < TAPS; ++t) acc[t] = b2[t];

    for (int c = 0; c < C_; ++c) {
        const float* wc = w1 + c * 27;
        float h0 = b1[c], h1 = 0.f, h2 = 0.f;
        #pragma unroll
        for (int r = 0; r < 3; ++r)
            #pragma unroll
            for (int j = 0; j < 3; ++j) {
                h0 = fmaf(wc[(0 * 3 + r) * 3 + j], win[0][r][j], h0);
                h1 = fmaf(wc[(1 * 3 + r) * 3 + j], win[1][r][j], h1);
                h2 = fmaf(wc[(2 * 3 + r) * 3 + j], win[2][r][j], h2);
            }
        const float hsum = fmaxf((h0 + h1) + h2, 0.f);   // ReLU

        const float4 wa = *(const float4*)&w2t[c][0];
        const float4 wb = *(const float4*)&w2t[c][4];
        const float  w8 = w2t[c][8];
        acc[0] = fmaf(wa.x, hsum, acc[0]);
        acc[1] = fmaf(wa.y, hsum, acc[1]);
        acc[2] = fmaf(wa.z, hsum, acc[2]);
        acc[3] = fmaf(wa.w, hsum, acc[3]);
        acc[4] = fmaf(wb.x, hsum, acc[4]);
        acc[5] = fmaf(wb.y, hsum, acc[5]);
        acc[6] = fmaf(wb.z, hsum, acc[6]);
        acc[7] = fmaf(wb.w, hsum, acc[7]);
        acc[8] = fmaf(w8,  hsum, acc[8]);
    }

    unsigned short* kr = kws + (size_t)(b * H_ + y) * (TAPS * W_);
    #pragma unroll
    for (int t = 0; t < TAPS; ++t) kr[t * W_ + x] = f2bf(acc[t]);
}

// ============================================================================
// Kernel 2 (gate): out = h * sigmoid(sum_taps shifted(h) * kern)
// R16 configuration (measured best, 82.8 us total): copy-shaped streaming.
//  - XCD swizzle ON (R17 A/B: removing it raised FETCH 71->102 MB)
//  - 1 channel per WAVE (block = b x 8-row strip x 4-channel group; 4096 blk)
//  - strip's 8 kern rows staged in LDS once (36 KB bf16, one barrier)
//  - steady state per wave per iter: 1 h load + 1 NT store
// ============================================================================
__global__ __launch_bounds__(256, 4)
void hsa_gate(const float* __restrict__ hin,
              const unsigned short* __restrict__ kws,
              float* __restrict__ out)
{
    __shared__ unsigned int ksh[8][KROW];   // 36 KB: 8 bf16 kern rows

    const int tid = threadIdx.x;
    const int bid = blockIdx.x;          // 0..4095
    // bijective XCD swizzle: 4096 = 8 XCDs x 512; each XCD owns one batch.
    const int nb  = (bid & 7) * 512 + (bid >> 3);
    const int b     = nb >> 9;           // 0..7
    const int strip = (nb >> 4) & 31;    // 0..31
    const int cg    = nb & 15;           // 0..15 (consecutive nb share kern rows)
    const int Y     = strip * 8;

    const int lane = tid & 63;
    const int wv   = tid >> 6;           // 0..3
    const int x0   = lane * 4;
    const int c0   = cg * 4 + wv;        // this wave's single channel

    const size_t plane = (size_t)H_ * W_;
    const float* hb = hin + ((size_t)b * C_ + c0) * plane;
    float*       ob = out + ((size_t)b * C_ + c0) * plane;
    const unsigned int* kbase = (const unsigned int*)kws + (size_t)b * H_ * KROW;

    const float lmask = (lane > 0)  ? 1.f : 0.f;
    const float rmask = (lane < 63) ? 1.f : 0.f;

    // ---- stage 8 kern rows cooperatively: 9216 u32 = 9 x u32x4 per thread --
    {
        const unsigned int* kr = kbase + (size_t)Y * KROW;  // rows contiguous
        unsigned int* ksf = &ksh[0][0];
        #pragma unroll
        for (int i = 0; i < 9; ++i) {
            const int idx = (tid + i * 256) * 4;
            *(u32x4*)(ksf + idx) = *(const u32x4*)(kr + idx);
        }
    }

    // ---- prologue: 3-row h window for this wave's channel ----
    f32x4 wA, wB, wC;
    {
        const int ym = (Y > 0) ? (Y - 1) : 0;   // clamped; masked via kt
        wA = *(const f32x4*)(hb + (size_t)ym      * W_ + x0);
        wB = *(const f32x4*)(hb + (size_t)Y       * W_ + x0);
        wC = *(const f32x4*)(hb + (size_t)(Y + 1) * W_ + x0);
    }
    __syncthreads();   // kern staging visible; only barrier in the kernel

    #pragma unroll
    for (int yy = 0; yy < 8; ++yy) {
        const int yg = Y + yy;

        // next h row (the wave's ONLY VMEM load this iter; sequential stream)
        f32x4 nxt;
        if (yy < 7) {
            const int yn = (yg + 2 < H_) ? (yg + 2) : (H_ - 1);
            nxt = *(const f32x4*)(hb + (size_t)yn * W_ + x0);
        }

        // kern taps from LDS (bf16 pairs -> f32 bit-ops, exact)
        f32x4 kt[TAPS];
        #pragma unroll
        for (int t = 0; t < TAPS; ++t) {
            const u32x2 w = *(const u32x2*)&ksh[yy][t * 128 + lane * 2];
            kt[t].x = __uint_as_float(w.x << 16);
            kt[t].y = __uint_as_float(w.x & 0xffff0000u);
            kt[t].z = __uint_as_float(w.y << 16);
            kt[t].w = __uint_as_float(w.y & 0xffff0000u);
        }

        // fold ALL boundary masks into kt
        const float m0 = (yg > 0)      ? 1.f : 0.f;
        const float m2 = (yg < H_ - 1) ? 1.f : 0.f;
        #pragma unroll
        for (int t = 0; t < 3; ++t) { kt[t] *= m0; kt[6 + t] *= m2; }
        kt[0].x *= lmask; kt[3].x *= lmask; kt[6].x *= lmask;
        kt[2].w *= rmask; kt[5].w *= rmask; kt[8].w *= rmask;

        // compute this channel (pure FMA + 2 shuffles per window row)
        float sim0 = 0.f, sim1 = 0.f, sim2 = 0.f, sim3 = 0.f;
        #pragma unroll
        for (int r = 0; r < 3; ++r) {
            const f32x4 cv = (r == 0) ? wA : (r == 1) ? wB : wC;
            const float l  = __shfl_up(cv.w, 1);    // x0-1 (lane0 masked via kt)
            const float rr = __shfl_down(cv.x, 1);  // x0+4 (lane63 masked via kt)
            const f32x4 k0 = kt[r * 3 + 0];
            const f32x4 k1 = kt[r * 3 + 1];
            const f32x4 k2 = kt[r * 3 + 2];
            sim0 = fmaf(l,    k0.x, fmaf(cv.x, k1.x, fmaf(cv.y, k2.x, sim0)));
            sim1 = fmaf(cv.x, k0.y, fmaf(cv.y, k1.y, fmaf(cv.z, k2.y, sim1)));
            sim2 = fmaf(cv.y, k0.z, fmaf(cv.z, k1.z, fmaf(cv.w, k2.z, sim2)));
            sim3 = fmaf(cv.z, k0.w, fmaf(cv.w, k1.w, fmaf(rr,   k2.w, sim3)));
        }

        // gate + non-temporal store (sequential write stream)
        f32x4 o;
        o.x = wB.x * __builtin_amdgcn_rcpf(1.f + __expf(-sim0));
        o.y = wB.y * __builtin_amdgcn_rcpf(1.f + __expf(-sim1));
        o.z = wB.z * __builtin_amdgcn_rcpf(1.f + __expf(-sim2));
        o.w = wB.w * __builtin_amdgcn_rcpf(1.f + __expf(-sim3));
        __builtin_nontemporal_store(o, (f32x4*)(ob + (size_t)yg * W_ + x0));

        // slide window (SSA renames after full unroll)
        if (yy < 7) { wA = wB; wB = wC; wC = nxt; }
    }
}

// ============================================================================
// Fallback: single fused kernel (used only if ws_size is too small)
// ============================================================================
__global__ __launch_bounds__(256, 4)
void hsa_fused(const float* __restrict__ lr,
               const float* __restrict__ hin,
               const float* __restrict__ w1,
               const float* __restrict__ b1,
               const float* __restrict__ w2,
               const float* __restrict__ b2,
               float* __restrict__ out)
{
    __shared__ float kernS[TAPS][W_];
    __shared__ float w2t[C_][12];

    const int tid = threadIdx.x;
    const int blk = blockIdx.x;
    const int b = blk / H_;
    const int y = blk % H_;

    for (int i = tid; i < TAPS * C_; i += 256) {
        const int t = i / C_;
        const int c = i % C_;
        w2t[c][t] = w2[i];
    }
    __syncthreads();

    {
        const int x = tid;
        float win[CIN][3][3];
        #pragma unroll
        for (int ci = 0; ci < CIN; ++ci)
            #pragma unroll
            for (int r = 0; r < 3; ++r) {
                const int yy = y + r - 1;
                const bool vy = (unsigned)yy < (unsigned)H_;
                const float* row = lr + ((size_t)(b * CIN + ci) * H_ + yy) * W_;
                win[ci][r][0] = (vy && x > 0)      ? row[x - 1] : 0.f;
                win[ci][r][1] = vy                  ? row[x]     : 0.f;
                win[ci][r][2] = (vy && x < W_ - 1) ? row[x + 1] : 0.f;
            }

        float acc[TAPS];
        #pragma unroll
        for (int t = 0; t < TAPS; ++t) acc[t] = b2[t];

        for (int c = 0; c < C_; ++c) {
            const float* wc = w1 + c * 27;
            float h0 = b1[c], h1 = 0.f, h2 = 0.f;
            #pragma unroll
            for (int r = 0; r < 3; ++r)
                #pragma unroll
                for (int j = 0; j < 3; ++j) {
                    h0 = fmaf(wc[(0 * 3 + r) * 3 + j], win[0][r][j], h0);
                    h1 = fmaf(wc[(1 * 3 + r) * 3 + j], win[1][r][j], h1);
                    h2 = fmaf(wc[(2 * 3 + r) * 3 + j], win[2][r][j], h2);
                }
            const float hsum = fmaxf((h0 + h1) + h2, 0.f);
            const float4 wa = *(const float4*)&w2t[c][0];
            const float4 wb = *(const float4*)&w2t[c][4];
            const float  w8 = w2t[c][8];
            acc[0] = fmaf(wa.x, hsum, acc[0]);
            acc[1] = fmaf(wa.y, hsum, acc[1]);
            acc[2] = fmaf(wa.z, hsum, acc[2]);
            acc[3] = fmaf(wa.w, hsum, acc[3]);
            acc[4] = fmaf(wb.x, hsum, acc[4]);
            acc[5] = fmaf(wb.y, hsum, acc[5]);
            acc[6] = fmaf(wb.z, hsum, acc[6]);
            acc[7] = fmaf(wb.w, hsum, acc[7]);
            acc[8] = fmaf(w8,  hsum, acc[8]);
        }
        #pragma unroll
        for (int t = 0; t < TAPS; ++t) kernS[t][x] = acc[t];
    }
    __syncthreads();

    const int lane = tid & 63;
    const int wav  = tid >> 6;
    const int x0   = lane * 4;

    float4 kt[TAPS];
    #pragma unroll
    for (int t = 0; t < TAPS; ++t) kt[t] = *(const float4*)&kernS[t][x0];

    #pragma unroll 4
    for (int cc = 0; cc < 16; ++cc) {
        const int c = wav * 16 + cc;
        const float* hb = hin + (size_t)(b * C_ + c) * H_ * W_;

        float4 rowv[3];
        float  lft[3], rgt[3];
        #pragma unroll
        for (int r = 0; r < 3; ++r) {
            const int yy = y + r - 1;
            const bool vy = (unsigned)yy < (unsigned)H_;
            float4 m;
            if (vy) m = *(const float4*)(hb + (size_t)yy * W_ + x0);
            else    m = make_float4(0.f, 0.f, 0.f, 0.f);
            rowv[r] = m;
            float l  = __shfl_up(m.w, 1);
            float rr = __shfl_down(m.x, 1);
            if (lane == 0)  l  = 0.f;
            if (lane == 63) rr = 0.f;
            lft[r] = l; rgt[r] = rr;
        }

        float sim0 = 0.f, sim1 = 0.f, sim2 = 0.f, sim3 = 0.f;
        #pragma unroll
        for (int r = 0; r < 3; ++r) {
            const float w6_0 = lft[r];
            const float w6_1 = rowv[r].x;
            const float w6_2 = rowv[r].y;
            const float w6_3 = rowv[r].z;
            const float w6_4 = rowv[r].w;
            const float w6_5 = rgt[r];
            { const float4 k4 = kt[r*3+0];
              sim0 = fmaf(w6_0, k4.x, sim0); sim1 = fmaf(w6_1, k4.y, sim1);
              sim2 = fmaf(w6_2, k4.z, sim2); sim3 = fmaf(w6_3, k4.w, sim3); }
            { const float4 k4 = kt[r*3+1];
              sim0 = fmaf(w6_1, k4.x, sim0); sim1 = fmaf(w6_2, k4.y, sim1);
              sim2 = fmaf(w6_3, k4.z, sim2); sim3 = fmaf(w6_4, k4.w, sim3); }
            { const float4 k4 = kt[r*3+2];
              sim0 = fmaf(w6_2, k4.x, sim0); sim1 = fmaf(w6_3, k4.y, sim1);
              sim2 = fmaf(w6_4, k4.z, sim2); sim3 = fmaf(w6_5, k4.w, sim3); }
        }

        float4 o;
        o.x = rowv[1].x * __builtin_amdgcn_rcpf(1.f + __expf(-sim0));
        o.y = rowv[1].y * __builtin_amdgcn_rcpf(1.f + __expf(-sim1));
        o.z = rowv[1].z * __builtin_amdgcn_rcpf(1.f + __expf(-sim2));
        o.w = rowv[1].w * __builtin_amdgcn_rcpf(1.f + __expf(-sim3));
        *(float4*)(out + ((size_t)(b * C_ + c) * H_ + y) * W_ + x0) = o;
    }
}

extern "C" void kernel_launch(void* const* d_in, const int* in_sizes, int n_in,
                              void* d_out, int out_size, void* d_ws, size_t ws_size,
                              hipStream_t stream) {
    const float* lr  = (const float*)d_in[0];  // [8,3,256,256]
    const float* hin = (const float*)d_in[1];  // [8,64,256,256]
    const float* w1  = (const float*)d_in[2];  // [64,3,3,3]
    const float* b1  = (const float*)d_in[3];  // [64]
    const float* w2  = (const float*)d_in[4];  // [9,64,1,1]
    const float* b2  = (const float*)d_in[5];  // [9]
    float* out = (float*)d_out;                // [8,64,256,256]

    const size_t kern_bytes = (size_t)B_ * H_ * TAPS * W_ * sizeof(unsigned short);

    if (ws_size >= kern_bytes) {
        unsigned short* kws = (unsigned short*)d_ws;
        hipLaunchKernelGGL(hsa_kern, dim3(B_ * H_), dim3(256), 0, stream,
                           lr, w1, b1, w2, b2, kws);
        // 8 batches x 32 strips(8 rows) x 16 channel-groups(4ch) = 4096 blocks
        hipLaunchKernelGGL(hsa_gate, dim3(4096), dim3(256), 0, stream,
                           hin, kws, out);
    } else {
        hipLaunchKernelGGL(hsa_fused, dim3(B_ * H_), dim3(256), 0, stream,
                           lr, hin, w1, b1, w2, b2, out);
    }
}